// Round 11
// baseline (279.467 us; speedup 1.0000x reference)
//
#include <hip/hip_runtime.h>
#include <hip/hip_bf16.h>

#define NN 384
#define CC 128
#define PP (NN*NN)      // 147456 positions
#define PB 128          // positions per block
#define NB (PP/PB)      // 1152 blocks
#define TPB 256         // 4 waves; each wave owns 32 rows (32x32x16 MFMA)

typedef __attribute__((ext_vector_type(8))) short bf16x8;
typedef __attribute__((ext_vector_type(16))) float f32x16;
typedef __attribute__((ext_vector_type(8))) unsigned short u16x8;

// D-layout for 32x32: row = (reg&3) + 8*(reg>>2) + 4*h, col = lane&31 (m74/m101)
#define ROWT(reg,h) ((((reg)&3) + 8*((reg)>>2)) + 4*(h))

__device__ __forceinline__ unsigned short f2bf(float f){
  // native RNE conversion (compiler emits v_cvt_pk_bf16_f32 and fuses pairs)
  __hip_bfloat16 h = __float2bfloat16(f);
  return __builtin_bit_cast(unsigned short, h);
}
__device__ __forceinline__ float bf2f(unsigned h){ return __uint_as_float(h<<16); }
__device__ __forceinline__ unsigned pack2(float a, float b){
  return (unsigned)f2bf(a) | ((unsigned)f2bf(b)<<16);
}
__device__ __forceinline__ float sigmoidf_(float x){
  return __fdividef(1.0f, 1.0f + __expf(-x));
}

// ---------------------------------------------------------------------------
// K0: 10 bf16 planes in PHASE order:
// 0 APH, 1 AGH, 2 APL, 3 AGL, 4 BPH, 5 BGH, 6 BPL, 7 BGL, 8 Z, 9 G
// each in 32x32-MFMA B-fragment order: chunk (k0*4+n)*64+l holds
// W[n*32+(l&31)][k0*16+(l>>5)*8 .. +7], k0 in [0,8).
// ---------------------------------------------------------------------------
__global__ __launch_bounds__(256) void k0_wprep(
    const float* __restrict__ wap, const float* __restrict__ wag,
    const float* __restrict__ wbp, const float* __restrict__ wbg,
    const float* __restrict__ wg,  const float* __restrict__ wz,
    unsigned short* __restrict__ wfrag){
  int tid = blockIdx.x*256 + threadIdx.x;      // 0..20479
  int plane = tid >> 11, chunk = tid & 2047;
  const float* W = (plane==0||plane==2) ? wap
                 : (plane==1||plane==3) ? wag
                 : (plane==4||plane==6) ? wbp
                 : (plane==5||plane==7) ? wbg
                 : (plane==8) ? wz : wg;
  bool lo = (plane==2)||(plane==3)||(plane==6)||(plane==7);
  int k0 = chunk >> 8, n = (chunk >> 6) & 3, l = chunk & 63;
  int o  = n*32 + (l & 31);
  int kb = k0*16 + ((l>>5)<<3);
  const float* s = W + o*128 + kb;
  u16x8 v;
  #pragma unroll
  for (int e=0;e<8;e++){
    float w = s[e];
    unsigned short hh = f2bf(w);
    v[e] = lo ? f2bf(w - bf2f(hh)) : hh;
  }
  *(u16x8*)(wfrag + (size_t)tid*8) = v;
}

// ---------------------------------------------------------------------------
// Stage one 8KB quarter-plane into a slot via global_load_lds (linear copy).
// ---------------------------------------------------------------------------
__device__ __forceinline__ void stage_q(const unsigned char* __restrict__ src_base,
                                        unsigned char* slot, int t){
  int wv = t>>6, l = t&63;
  const unsigned char* src = src_base + wv*2048 + l*16;
  unsigned char* dst = slot + wv*2048;
  #pragma unroll
  for (int i=0;i<2;i++)
    __builtin_amdgcn_global_load_lds(
        (const __attribute__((address_space(1))) unsigned int*)(src + i*1024),
        (__attribute__((address_space(3))) unsigned int*)(dst + i*1024),
        16, 0, 0);
}

// ---------------------------------------------------------------------------
// Quarter-plane passes: 2 k-steps x 4 n. Slot chunk (kr*4+n)*1024 + l*16 holds
// k0 = kbase+kr (kbase = 2*(quarter%4)). A-frag kbase selects a[kbase..kbase+1].
// ---------------------------------------------------------------------------
__device__ __forceinline__ void q_H(const bf16x8* a, int kbase,
    const unsigned char* slot, int l, f32x16* acc){
  #pragma unroll
  for (int kr=0;kr<2;kr++){
    #pragma unroll
    for (int n=0;n<4;n++){
      bf16x8 f = *(const bf16x8*)(slot + (kr*4+n)*1024 + l*16);
      acc[n] = __builtin_amdgcn_mfma_f32_32x32x16_bf16(a[kbase+kr], f, acc[n],0,0,0);
    }
  }
}
__device__ __forceinline__ void q_HL(const bf16x8* aH, const bf16x8* aL, int kbase,
    const unsigned char* slot, int l, f32x16* acc){
  #pragma unroll
  for (int kr=0;kr<2;kr++){
    #pragma unroll
    for (int n=0;n<4;n++){
      bf16x8 f = *(const bf16x8*)(slot + (kr*4+n)*1024 + l*16);
      acc[n] = __builtin_amdgcn_mfma_f32_32x32x16_bf16(aH[kbase+kr], f, acc[n],0,0,0);
      acc[n] = __builtin_amdgcn_mfma_f32_32x32x16_bf16(aL[kbase+kr], f, acc[n],0,0,0);
    }
  }
}
__device__ __forceinline__ void splat(const float* __restrict__ b, int c, f32x16* acc){
  #pragma unroll
  for (int n=0;n<4;n++){
    float v = b[n*32+c];
    #pragma unroll
    for (int r=0;r<16;r++) acc[n][r]=v;
  }
}
// A-frag extraction from [row][col] XOR-swizzled bf16 tile (R8/R10-verified).
__device__ __forceinline__ void extract8(const unsigned char* R0, int row, int h,
                                         bf16x8 a[8]){
  int swz = (row&7)<<4;
  #pragma unroll
  for (int k0=0;k0<8;k0++){
    unsigned off = (unsigned)(row*256 + (((k0<<5) + (h<<4)) ^ swz));
    a[k0] = *(const bf16x8*)(R0 + off);
  }
}

// ---------------------------------------------------------------------------
// Fused kernel (R10 components; quarter-plane 2-slot pipeline, 40 phases).
// LDS 48KB: R0[0,32K) zn->xa->xn ; slots [32K,40K),[40K,48K). 3 blocks/CU.
// ---------------------------------------------------------------------------
__global__ __launch_bounds__(TPB,3) void k_fused(
    const float* __restrict__ z, const float* __restrict__ mask,
    const float* __restrict__ bap, const float* __restrict__ bag,
    const float* __restrict__ bbp, const float* __restrict__ bbg,
    const float* __restrict__ bgg, const float* __restrict__ bz,
    const float* __restrict__ lniw, const float* __restrict__ lnib,
    const float* __restrict__ lnow, const float* __restrict__ lnob,
    const unsigned short* __restrict__ wfrag,
    float* __restrict__ out){
  __shared__ unsigned char lds[49152];
  unsigned char* R0 = lds;
  const unsigned char* wfrag8 = (const unsigned char*)wfrag;
  const int t = threadIdx.x;
  const int pos0 = blockIdx.x * PB;
  const int rowg = t>>5, c4 = (t&31)<<2;

  // prologue: stage quarter 0 -> slot 0 (drains at first barrier)
  stage_q(wfrag8, lds + 32768, t);

  // ---- P1: LN(z), two-pass var; znH -> R0; keep normalized f32 in nv ----
  float4 nv[16];
  {
    float4 lw = *(const float4*)(lniw + c4);
    float4 lb = *(const float4*)(lnib + c4);
    #pragma unroll
    for (int it=0; it<16; ++it){
      int row = it*8 + rowg;
      float4 v = *(const float4*)(z + (size_t)(pos0+row)*CC + c4);
      float s = v.x+v.y+v.z+v.w;
      #pragma unroll
      for (int mm=1; mm<32; mm<<=1) s += __shfl_xor(s,mm);
      float mu = s*(1.0f/128.0f);
      float d0=v.x-mu, d1=v.y-mu, d2=v.z-mu, d3=v.w-mu;
      float ss = d0*d0+d1*d1+d2*d2+d3*d3;
      #pragma unroll
      for (int mm=1; mm<32; mm<<=1) ss += __shfl_xor(ss,mm);
      float rstd = rsqrtf(ss*(1.0f/128.0f) + 1e-5f);
      nv[it].x = d0*rstd*lw.x+lb.x; nv[it].y = d1*rstd*lw.y+lb.y;
      nv[it].z = d2*rstd*lw.z+lb.z; nv[it].w = d3*rstd*lw.w+lb.w;
      unsigned off = (unsigned)(row*256 + ((c4<<1) ^ ((row&7)<<4)));
      *(uint2*)(R0 + off) = make_uint2(pack2(nv[it].x, nv[it].y),
                                       pack2(nv[it].z, nv[it].w));
    }
  }
  __syncthreads();

  const int wv = t>>6, l = t&63;
  const int c  = l&31, h = l>>5;
  const int row0 = wv*32;

  // ---- H->L swap with full barrier discipline (R10 verbatim) ----
  bf16x8 aH[8], aLo[8];
  extract8(R0, row0+c, h, aH);
  __syncthreads();
  #pragma unroll
  for (int it=0;it<16;++it){
    int row = it*8 + rowg;
    float l0 = nv[it].x - bf2f(f2bf(nv[it].x)), l1 = nv[it].y - bf2f(f2bf(nv[it].y));
    float l2 = nv[it].z - bf2f(f2bf(nv[it].z)), l3 = nv[it].w - bf2f(f2bf(nv[it].w));
    unsigned off = (unsigned)(row*256 + ((c4<<1) ^ ((row&7)<<4)));
    *(uint2*)(R0+off) = make_uint2(pack2(l0,l1), pack2(l2,l3));
  }
  __syncthreads();
  extract8(R0, row0+c, h, aLo);

  f32x16 accp[4], accg[4];
#define SL(p) (lds + 32768 + (((p)&1)<<13))
#define PH(p) do{ __syncthreads(); \
    if ((p)+1 < 40) stage_q(wfrag8 + ((size_t)((p)+1))*8192, SL((p)+1), t); }while(0)

  // ---- a: accp = bap + (aH+aLo)@WpH + aH@WpL ; accg likewise ----
  PH(0);  splat(bap,c,accp); q_HL(aH,aLo,0,SL(0), l,accp);   // APH q0
  PH(1);  q_HL(aH,aLo,2,SL(1), l,accp);                      // APH q1
  PH(2);  q_HL(aH,aLo,4,SL(2), l,accp);                      // APH q2
  PH(3);  q_HL(aH,aLo,6,SL(3), l,accp);                      // APH q3
  PH(4);  splat(bag,c,accg); q_HL(aH,aLo,0,SL(4), l,accg);   // AGH q0
  PH(5);  q_HL(aH,aLo,2,SL(5), l,accg);                      // AGH q1
  PH(6);  q_HL(aH,aLo,4,SL(6), l,accg);                      // AGH q2
  PH(7);  q_HL(aH,aLo,6,SL(7), l,accg);                      // AGH q3
  PH(8);  q_H(aH,0,SL(8), l,accp);                           // APL q0
  PH(9);  q_H(aH,2,SL(9), l,accp);                           // APL q1
  PH(10); q_H(aH,4,SL(10),l,accp);                           // APL q2
  PH(11); q_H(aH,6,SL(11),l,accp);                           // APL q3
  PH(12); q_H(aH,0,SL(12),l,accg);                           // AGL q0
  PH(13); q_H(aH,2,SL(13),l,accg);                           // AGL q1
  PH(14); q_H(aH,4,SL(14),l,accg);                           // AGL q2
  PH(15); q_H(aH,6,SL(15),l,accg);                           // AGL q3
  // ---- xa = a*sig(ga)*mask -> park bf16 frag-order in own R0 region ----
  {
    unsigned char* xr = R0 + wv*8192;
    #pragma unroll
    for (int n=0;n<4;n++){
      #pragma unroll
      for (int j=0;j<8;j++){
        float m0 = mask[pos0+row0+ROWT(2*j,  h)];
        float m1 = mask[pos0+row0+ROWT(2*j+1,h)];
        float a0 = accp[n][2*j]  *sigmoidf_(accg[n][2*j])  *m0;
        float a1 = accp[n][2*j+1]*sigmoidf_(accg[n][2*j+1])*m1;
        *(unsigned*)(xr + (n*8+j)*256 + l*4) = pack2(a0,a1);
      }
    }
  }
  // ---- b ----
  PH(16); splat(bbp,c,accp); q_HL(aH,aLo,0,SL(16),l,accp);   // BPH q0
  PH(17); q_HL(aH,aLo,2,SL(17),l,accp);                      // BPH q1
  PH(18); q_HL(aH,aLo,4,SL(18),l,accp);                      // BPH q2
  PH(19); q_HL(aH,aLo,6,SL(19),l,accp);                      // BPH q3
  PH(20); splat(bbg,c,accg); q_HL(aH,aLo,0,SL(20),l,accg);   // BGH q0
  PH(21); q_HL(aH,aLo,2,SL(21),l,accg);                      // BGH q1
  PH(22); q_HL(aH,aLo,4,SL(22),l,accg);                      // BGH q2
  PH(23); q_HL(aH,aLo,6,SL(23),l,accg);                      // BGH q3 (last aLo)
  PH(24); q_H(aH,0,SL(24),l,accp);                           // BPL q0
  PH(25); q_H(aH,2,SL(25),l,accp);                           // BPL q1
  PH(26); q_H(aH,4,SL(26),l,accp);                           // BPL q2
  PH(27); q_H(aH,6,SL(27),l,accp);                           // BPL q3
  PH(28); q_H(aH,0,SL(28),l,accg);                           // BGL q0
  PH(29); q_H(aH,2,SL(29),l,accg);                           // BGL q1
  PH(30); q_H(aH,4,SL(30),l,accg);                           // BGL q2
  PH(31); q_H(aH,6,SL(31),l,accg);                           // BGL q3
  // ---- x = xa*b ; LN(x) ; xn -> R0 ; extract a2 (R10 verbatim, wave-local) ----
  bf16x8 a2[8];
  {
    f32x16 xv[4];
    const unsigned char* xr = R0 + wv*8192;
    #pragma unroll
    for (int n=0;n<4;n++){
      #pragma unroll
      for (int j=0;j<8;j++){
        float m0 = mask[pos0+row0+ROWT(2*j,  h)];
        float m1 = mask[pos0+row0+ROWT(2*j+1,h)];
        unsigned w = *(const unsigned*)(xr + (n*8+j)*256 + l*4);
        float b0 = accp[n][2*j]  *sigmoidf_(accg[n][2*j])  *m0;
        float b1 = accp[n][2*j+1]*sigmoidf_(accg[n][2*j+1])*m1;
        xv[n][2*j]   = bf2f(w & 0xffffu)*b0;
        xv[n][2*j+1] = bf2f(w >> 16)   *b1;
      }
    }
    float lw4[4], lb4[4];
    #pragma unroll
    for (int n=0;n<4;n++){ lw4[n]=lnow[n*32+c]; lb4[n]=lnob[n*32+c]; }
    #pragma unroll
    for (int reg=0; reg<16; ++reg){
      float s=0.f;
      #pragma unroll
      for (int n=0;n<4;n++) s += xv[n][reg];
      #pragma unroll
      for (int mm=1; mm<32; mm<<=1) s += __shfl_xor(s,mm);
      float mu = s*(1.0f/128.0f);
      float ss=0.f;
      #pragma unroll
      for (int n=0;n<4;n++){ float d=xv[n][reg]-mu; ss+=d*d; }
      #pragma unroll
      for (int mm=1; mm<32; mm<<=1) ss += __shfl_xor(ss,mm);
      float rstd = rsqrtf(ss*(1.0f/128.0f)+1e-5f);
      int row = row0 + ROWT(reg,h);
      int swz = (row&7)<<4;
      #pragma unroll
      for (int n=0;n<4;n++){
        int colb = (n*32+c)*2;
        float vvv = (xv[n][reg]-mu)*rstd*lw4[n]+lb4[n];
        *(unsigned short*)(R0 + row*256 + (colb ^ swz)) = f2bf(vvv);
      }
    }
    extract8(R0, row0+c, h, a2);   // wave-local rows; compiler orders ds ops
  }
  // ---- final: o = xn@Wz+bz ; gv = zn@Wg+bgg ----
  PH(32); splat(bz,c,accp);  q_H(a2,0,SL(32),l,accp);        // Z q0
  PH(33); q_H(a2,2,SL(33),l,accp);                           // Z q1
  PH(34); q_H(a2,4,SL(34),l,accp);                           // Z q2
  PH(35); q_H(a2,6,SL(35),l,accp);                           // Z q3
  PH(36); splat(bgg,c,accg); q_H(aH,0,SL(36),l,accg);        // G q0
  PH(37); q_H(aH,2,SL(37),l,accg);                           // G q1
  PH(38); q_H(aH,4,SL(38),l,accg);                           // G q2
  PH(39); q_H(aH,6,SL(39),l,accg);                           // G q3
  // ---- epilogue: out = o * sig(gv) ----
  #pragma unroll
  for (int n=0;n<4;n++){
    #pragma unroll
    for (int reg=0; reg<16; ++reg){
      int row = row0 + ROWT(reg,h);
      out[(size_t)(pos0+row)*CC + n*32 + c] = accp[n][reg]*sigmoidf_(accg[n][reg]);
    }
  }
#undef PH
#undef SL
}

extern "C" void kernel_launch(void* const* d_in, const int* in_sizes, int n_in,
                              void* d_out, int out_size, void* d_ws, size_t ws_size,
                              hipStream_t stream){
  const float* z     = (const float*)d_in[0];
  const float* mask  = (const float*)d_in[1];
  const float* w_ap  = (const float*)d_in[2];
  const float* b_ap  = (const float*)d_in[3];
  const float* w_bp  = (const float*)d_in[4];
  const float* b_bp  = (const float*)d_in[5];
  const float* w_ag  = (const float*)d_in[6];
  const float* b_ag  = (const float*)d_in[7];
  const float* w_bg  = (const float*)d_in[8];
  const float* b_bg  = (const float*)d_in[9];
  const float* w_g   = (const float*)d_in[10];
  const float* b_g   = (const float*)d_in[11];
  const float* w_z   = (const float*)d_in[12];
  const float* b_z   = (const float*)d_in[13];
  const float* ln_in_w  = (const float*)d_in[14];
  const float* ln_in_b  = (const float*)d_in[15];
  const float* ln_out_w = (const float*)d_in[16];
  const float* ln_out_b = (const float*)d_in[17];

  unsigned short* wfrag = (unsigned short*)d_ws;   // 10 planes * 32KB = 320KB

  k0_wprep<<<80, 256, 0, stream>>>(w_ap, w_ag, w_bp, w_bg, w_g, w_z, wfrag);
  k_fused<<<NB, TPB, 0, stream>>>(z, mask, b_ap, b_ag, b_bp, b_bg, b_g, b_z,
                                  ln_in_w, ln_in_b, ln_out_w, ln_out_b,
                                  wfrag, (float*)d_out);
}

// Round 12
// 111.153 us; speedup vs baseline: 2.5143x; 2.5143x over previous
//
#include <hip/hip_runtime.h>
#include <hip/hip_bf16.h>
#include <hip/hip_fp16.h>

#define NN 384
#define CC 128
#define PP (NN*NN)      // 147456 positions
#define PB 64           // positions per block
#define NB (PP/PB)      // 2304 blocks
#define TPB 256         // 4 waves; each wave owns one 16-row stripe (16x16x32 MFMA)

typedef __attribute__((ext_vector_type(8))) short bf16x8;
typedef __attribute__((ext_vector_type(4))) float f32x4;
typedef __attribute__((ext_vector_type(8))) unsigned short u16x8;

// 8 weight planes (32KB each) in PHASE order:
// 0 AGH, 1 APH, 2 APL, 3 BGH, 4 BPH, 5 BPL, 6 G, 7 Z
// Plane layout (R7-proven): chunk (k0*8+n)*64+l holds
// W[n*16+(l&15)][k0*32+(l>>4)*8 .. +7], k0 in [0,4).
// Quarter q = k0=q block = bytes [q*8192, q*8192+8192).

__device__ __forceinline__ unsigned short f2bf(float f){
  __hip_bfloat16 h = __float2bfloat16(f);
  return __builtin_bit_cast(unsigned short, h);
}
__device__ __forceinline__ float bf2f(unsigned h){ return __uint_as_float(h<<16); }
__device__ __forceinline__ unsigned pack2(float a, float b){
  return (unsigned)f2bf(a) | ((unsigned)f2bf(b)<<16);
}
__device__ __forceinline__ float sigmoidf_(float x){
  return __fdividef(1.0f, 1.0f + __expf(-x));
}
__device__ __forceinline__ unsigned short f2h(float f){
  __half h = __float2half(f);
  return __builtin_bit_cast(unsigned short, h);
}
__device__ __forceinline__ float h2f(unsigned short u){
  __half h = __builtin_bit_cast(__half, u);
  return __half2float(h);
}

// ---------------------------------------------------------------------------
__global__ __launch_bounds__(256) void k0_wprep(
    const float* __restrict__ wap, const float* __restrict__ wag,
    const float* __restrict__ wbp, const float* __restrict__ wbg,
    const float* __restrict__ wg,  const float* __restrict__ wz,
    unsigned short* __restrict__ wfrag){
  int tid = blockIdx.x*256 + threadIdx.x;      // 0..16383
  int plane = tid >> 11, chunk = tid & 2047;
  const float* W = (plane==0) ? wag
                 : (plane==1||plane==2) ? wap
                 : (plane==3) ? wbg
                 : (plane==4||plane==5) ? wbp
                 : (plane==6) ? wg : wz;
  bool lo = (plane==2)||(plane==5);
  int k0 = chunk >> 9, n = (chunk >> 6) & 7, l = chunk & 63;
  int o  = n*16 + (l & 15);
  int kb = k0*32 + ((l>>4)<<3);
  const float* s = W + o*128 + kb;
  u16x8 v;
  #pragma unroll
  for (int e=0;e<8;e++){
    float w = s[e];
    unsigned short hh = f2bf(w);
    v[e] = lo ? f2bf(w - bf2f(hh)) : hh;
  }
  *(u16x8*)(wfrag + (size_t)tid*8) = v;
}

// ---------------------------------------------------------------------------
// Stage one 8KB plane-quarter into a slot (global_load_lds, zero staging regs).
// ---------------------------------------------------------------------------
__device__ __forceinline__ void stage_q(const unsigned char* __restrict__ src_base,
                                        unsigned char* slot, int t){
  int wv = t>>6, l = t&63;
  const unsigned char* src = src_base + wv*2048 + l*16;
  unsigned char* dst = slot + wv*2048;
  #pragma unroll
  for (int i=0;i<2;i++)
    __builtin_amdgcn_global_load_lds(
        (const __attribute__((address_space(1))) unsigned int*)(src + i*1024),
        (__attribute__((address_space(3))) unsigned int*)(dst + i*1024),
        16, 0, 0);
}

// ---------------------------------------------------------------------------
// Quarter passes (k0=q fixed): 8 n-frags. Slot offset n*1024 + l*16.
// A-frag: row=row0+(l&15), k=q*32+(l>>4)*8+e. D: row=row0+(l>>4)*4+r, col=n*16+(l&15).
// ---------------------------------------------------------------------------
__device__ __forceinline__ void q_H(const bf16x8* a, int q,
    const unsigned char* slot, int l, f32x4* acc){
  #pragma unroll
  for (int n=0;n<8;n++){
    bf16x8 f = *(const bf16x8*)(slot + n*1024 + l*16);
    acc[n] = __builtin_amdgcn_mfma_f32_16x16x32_bf16(a[q], f, acc[n], 0,0,0);
  }
}
__device__ __forceinline__ void q_HL(const bf16x8* aH, const bf16x8* aL, int q,
    const unsigned char* slot, int l, f32x4* acc){
  #pragma unroll
  for (int n=0;n<8;n++){
    bf16x8 f = *(const bf16x8*)(slot + n*1024 + l*16);
    acc[n] = __builtin_amdgcn_mfma_f32_16x16x32_bf16(aH[q], f, acc[n], 0,0,0);
    acc[n] = __builtin_amdgcn_mfma_f32_16x16x32_bf16(aL[q], f, acc[n], 0,0,0);
  }
}
__device__ __forceinline__ void bias_init(const float* __restrict__ b, int cb,
                                          f32x4* acc){
  #pragma unroll
  for (int n=0;n<8;n++){
    float v = b[n*16 + cb];
    f32x4 iv = {v,v,v,v};
    acc[n]=iv;
  }
}
// A-frag extraction from [row][col] XOR-swizzled bf16 64x256B tile (R7-proven).
__device__ __forceinline__ void extract4(const unsigned char* base, int row0,
                                         int l, bf16x8 a[4]){
  int row = row0 + (l&15);
  int swz = (row&7)<<4;
  #pragma unroll
  for (int k0=0;k0<4;k0++){
    unsigned off = (unsigned)(row*256 + ((((l>>4)<<4) + (k0<<6)) ^ swz));
    a[k0] = *(const bf16x8*)(base + off);
  }
}

// ---------------------------------------------------------------------------
// Fused kernel: 32 quarter-phases, 2-slot rotation, stage-1-ahead.
// LDS 48KB: bufH[0,16K) znH->xa ; bufL[16K,32K) znL->xn ; slots [32K,48K).
// Gate-then-proj sequencing: accp/accg never coexist -> ~100 unified regs.
// ---------------------------------------------------------------------------
__global__ __launch_bounds__(TPB,2) void k_fused(
    const float* __restrict__ z, const float* __restrict__ mask,
    const float* __restrict__ bap, const float* __restrict__ bag,
    const float* __restrict__ bbp, const float* __restrict__ bbg,
    const float* __restrict__ bgg, const float* __restrict__ bz,
    const float* __restrict__ lniw, const float* __restrict__ lnib,
    const float* __restrict__ lnow, const float* __restrict__ lnob,
    const unsigned short* __restrict__ wfrag,
    float* __restrict__ out){
  __shared__ unsigned char lds[49152];
  unsigned char* bufH = lds;            // 16KB: znH, later xa (bf16, pair-order)
  unsigned char* bufL = lds + 16384;    // 16KB: znL, later xn
  const unsigned char* wfrag8 = (const unsigned char*)wfrag;
  const int t = threadIdx.x;
  const int pos0 = blockIdx.x * PB;
  const int rowg = t>>5, c4 = (t&31)<<2;

  // prologue: stage quarter 0 (AGH q0) -> slot 0
  stage_q(wfrag8, lds + 32768, t);

  // ---- P1: LN(z), two-pass var, hi/lo split (R7 verbatim) ----
  {
    float4 lw = *(const float4*)(lniw + c4);
    float4 lb = *(const float4*)(lnib + c4);
    #pragma unroll
    for (int it=0; it<8; ++it){
      int row = it*8 + rowg;
      float4 v = *(const float4*)(z + (size_t)(pos0+row)*CC + c4);
      float s = v.x+v.y+v.z+v.w;
      #pragma unroll
      for (int mm=1; mm<32; mm<<=1) s += __shfl_xor(s,mm);
      float mu = s*(1.0f/128.0f);
      float d0=v.x-mu, d1=v.y-mu, d2=v.z-mu, d3=v.w-mu;
      float ss = d0*d0+d1*d1+d2*d2+d3*d3;
      #pragma unroll
      for (int mm=1; mm<32; mm<<=1) ss += __shfl_xor(ss,mm);
      float rstd = rsqrtf(ss*(1.0f/128.0f) + 1e-5f);
      float n0=d0*rstd*lw.x+lb.x, n1=d1*rstd*lw.y+lb.y;
      float n2=d2*rstd*lw.z+lb.z, n3=d3*rstd*lw.w+lb.w;
      unsigned short h0=f2bf(n0), h1=f2bf(n1), h2=f2bf(n2), h3=f2bf(n3);
      unsigned off = (unsigned)(row*256 + ((c4<<1) ^ ((row&7)<<4)));
      *(uint2*)(bufH + off) = make_uint2((unsigned)h0|((unsigned)h1<<16),
                                         (unsigned)h2|((unsigned)h3<<16));
      *(uint2*)(bufL + off) = make_uint2(pack2(n0-bf2f(h0), n1-bf2f(h1)),
                                         pack2(n2-bf2f(h2), n3-bf2f(h3)));
    }
  }
  __syncthreads();

  const int wv = t>>6, l = t&63;
  const int cb = l&15;            // D col-within-16 / A row-within-16
  const int g4 = (l>>4)<<2;       // D row-quad base
  const int row0 = wv*16;

  bf16x8 aH[4], aLo[4];
  extract4(bufH, row0, l, aH);
  extract4(bufL, row0, l, aLo);

  float mk[4];
  #pragma unroll
  for (int r=0;r<4;r++) mk[r] = mask[pos0 + row0 + g4 + r];

  f32x4 accp[8], accg[8];
  unsigned gpk[16];     // packed f16 gate (32 values)

#define SL(p) (lds + 32768 + (((p)&1)<<13))
#define PH(p) do{ __syncthreads(); \
    if ((p)+1 < 32) stage_q(wfrag8 + ((size_t)((p)+1))*8192, SL((p)+1), t); }while(0)

  // ---- a-gate (hi-only), then pack f16 and free accg ----
  PH(0);  bias_init(bag,cb,accg); q_H(aH,0,SL(0), l,accg);
  PH(1);  q_H(aH,1,SL(1), l,accg);
  PH(2);  q_H(aH,2,SL(2), l,accg);
  PH(3);  q_H(aH,3,SL(3), l,accg);
  #pragma unroll
  for (int n=0;n<8;n++)
    #pragma unroll
    for (int rp=0;rp<2;rp++)
      gpk[n*2+rp] = (unsigned)f2h(sigmoidf_(accg[n][2*rp]))
                  | ((unsigned)f2h(sigmoidf_(accg[n][2*rp+1]))<<16);
  // ---- a-proj (f32-grade) ----
  PH(4);  bias_init(bap,cb,accp); q_HL(aH,aLo,0,SL(4), l,accp);
  PH(5);  q_HL(aH,aLo,1,SL(5), l,accp);
  PH(6);  q_HL(aH,aLo,2,SL(6), l,accp);
  PH(7);  q_HL(aH,aLo,3,SL(7), l,accp);
  PH(8);  q_H(aH,0,SL(8), l,accp);
  PH(9);  q_H(aH,1,SL(9), l,accp);
  PH(10); q_H(aH,2,SL(10),l,accp);
  PH(11); q_H(aH,3,SL(11),l,accp);
  // ---- xa = a*sig(ga)*mask -> park bf16 pair-order in own bufH region ----
  {
    unsigned char* xr = bufH + wv*4096;
    #pragma unroll
    for (int n=0;n<8;n++){
      #pragma unroll
      for (int rp=0;rp<2;rp++){
        float g0 = h2f((unsigned short)(gpk[n*2+rp] & 0xffffu));
        float g1 = h2f((unsigned short)(gpk[n*2+rp] >> 16));
        float a0 = accp[n][2*rp]  *g0*mk[2*rp];
        float a1 = accp[n][2*rp+1]*g1*mk[2*rp+1];
        *(unsigned*)(xr + (n*2+rp)*256 + l*4) = pack2(a0,a1);
      }
    }
  }
  // ---- b-gate (hi-only), pack ----
  PH(12); bias_init(bbg,cb,accg); q_H(aH,0,SL(12),l,accg);
  PH(13); q_H(aH,1,SL(13),l,accg);
  PH(14); q_H(aH,2,SL(14),l,accg);
  PH(15); q_H(aH,3,SL(15),l,accg);
  #pragma unroll
  for (int n=0;n<8;n++)
    #pragma unroll
    for (int rp=0;rp<2;rp++)
      gpk[n*2+rp] = (unsigned)f2h(sigmoidf_(accg[n][2*rp]))
                  | ((unsigned)f2h(sigmoidf_(accg[n][2*rp+1]))<<16);
  // ---- b-proj ----
  PH(16); bias_init(bbp,cb,accp); q_HL(aH,aLo,0,SL(16),l,accp);
  PH(17); q_HL(aH,aLo,1,SL(17),l,accp);
  PH(18); q_HL(aH,aLo,2,SL(18),l,accp);
  PH(19); q_HL(aH,aLo,3,SL(19),l,accp);     // last aLo use
  PH(20); q_H(aH,0,SL(20),l,accp);
  PH(21); q_H(aH,1,SL(21),l,accp);
  PH(22); q_H(aH,2,SL(22),l,accp);
  PH(23); q_H(aH,3,SL(23),l,accp);
  // ---- x = xa*b ; LN(x) in-register ; xn -> bufL ; extract a2 (wave-local) ----
  bf16x8 a2[4];
  {
    f32x4 xv[8];
    const unsigned char* xr = bufH + wv*4096;
    #pragma unroll
    for (int n=0;n<8;n++){
      #pragma unroll
      for (int rp=0;rp<2;rp++){
        float g0 = h2f((unsigned short)(gpk[n*2+rp] & 0xffffu));
        float g1 = h2f((unsigned short)(gpk[n*2+rp] >> 16));
        unsigned w = *(const unsigned*)(xr + (n*2+rp)*256 + l*4);
        float b0 = accp[n][2*rp]  *g0*mk[2*rp];
        float b1 = accp[n][2*rp+1]*g1*mk[2*rp+1];
        xv[n][2*rp]   = bf2f(w & 0xffffu)*b0;
        xv[n][2*rp+1] = bf2f(w >> 16)   *b1;
      }
    }
    float lw8[8], lb8[8];
    #pragma unroll
    for (int n=0;n<8;n++){ lw8[n]=lnow[n*16+cb]; lb8[n]=lnob[n*16+cb]; }
    #pragma unroll
    for (int r=0;r<4;r++){
      float s=0.f;
      #pragma unroll
      for (int n=0;n<8;n++) s += xv[n][r];
      #pragma unroll
      for (int mm=1; mm<16; mm<<=1) s += __shfl_xor(s,mm);
      float mu = s*(1.0f/128.0f);
      float ss=0.f;
      #pragma unroll
      for (int n=0;n<8;n++){ float d = xv[n][r]-mu; ss += d*d; }
      #pragma unroll
      for (int mm=1; mm<16; mm<<=1) ss += __shfl_xor(ss,mm);
      float rstd = rsqrtf(ss*(1.0f/128.0f) + 1e-5f);
      int row = row0 + g4 + r;
      int swz = (row&7)<<4;
      #pragma unroll
      for (int n=0;n<8;n++){
        int colb = (n*16+cb)*2;
        float vvv = (xv[n][r]-mu)*rstd*lw8[n]+lb8[n];
        *(unsigned short*)(bufL + row*256 + (colb ^ swz)) = f2bf(vvv);
      }
    }
    extract4(bufL, row0, l, a2);   // own rows; same-wave ds ordering
  }
  // ---- g-gate (zn@Wg, hi-only) -> pack ; final proj (xn@Wz) ----
  PH(24); bias_init(bgg,cb,accg); q_H(aH,0,SL(24),l,accg);
  PH(25); q_H(aH,1,SL(25),l,accg);
  PH(26); q_H(aH,2,SL(26),l,accg);
  PH(27); q_H(aH,3,SL(27),l,accg);
  #pragma unroll
  for (int n=0;n<8;n++)
    #pragma unroll
    for (int rp=0;rp<2;rp++)
      gpk[n*2+rp] = (unsigned)f2h(sigmoidf_(accg[n][2*rp]))
                  | ((unsigned)f2h(sigmoidf_(accg[n][2*rp+1]))<<16);
  PH(28); bias_init(bz,cb,accp); q_H(a2,0,SL(28),l,accp);
  PH(29); q_H(a2,1,SL(29),l,accp);
  PH(30); q_H(a2,2,SL(30),l,accp);
  PH(31); q_H(a2,3,SL(31),l,accp);
  // ---- epilogue: out = o * sig(gv) ----
  #pragma unroll
  for (int n=0;n<8;n++){
    #pragma unroll
    for (int r=0;r<4;r++){
      int row = row0 + g4 + r;
      float gg = h2f((unsigned short)((gpk[n*2+(r>>1)] >> ((r&1)*16)) & 0xffffu));
      out[(size_t)(pos0+row)*CC + n*16 + cb] = accp[n][r]*gg;
    }
  }
#undef PH
#undef SL
}

extern "C" void kernel_launch(void* const* d_in, const int* in_sizes, int n_in,
                              void* d_out, int out_size, void* d_ws, size_t ws_size,
                              hipStream_t stream){
  const float* z     = (const float*)d_in[0];
  const float* mask  = (const float*)d_in[1];
  const float* w_ap  = (const float*)d_in[2];
  const float* b_ap  = (const float*)d_in[3];
  const float* w_bp  = (const float*)d_in[4];
  const float* b_bp  = (const float*)d_in[5];
  const float* w_ag  = (const float*)d_in[6];
  const float* b_ag  = (const float*)d_in[7];
  const float* w_bg  = (const float*)d_in[8];
  const float* b_bg  = (const float*)d_in[9];
  const float* w_g   = (const float*)d_in[10];
  const float* b_g   = (const float*)d_in[11];
  const float* w_z   = (const float*)d_in[12];
  const float* b_z   = (const float*)d_in[13];
  const float* ln_in_w  = (const float*)d_in[14];
  const float* ln_in_b  = (const float*)d_in[15];
  const float* ln_out_w = (const float*)d_in[16];
  const float* ln_out_b = (const float*)d_in[17];

  unsigned short* wfrag = (unsigned short*)d_ws;   // 8 planes * 32KB = 256KB

  k0_wprep<<<64, 256, 0, stream>>>(w_ap, w_ag, w_bp, w_bg, w_g, w_z, wfrag);
  k_fused<<<NB, TPB, 0, stream>>>(z, mask, b_ap, b_ag, b_bp, b_bg, b_g, b_z,
                                  ln_in_w, ln_in_b, ln_out_w, ln_out_b,
                                  wfrag, (float*)d_out);
}